// Round 2
// baseline (774.764 us; speedup 1.0000x reference)
//
#include <hip/hip_runtime.h>

// ShapeAwareRoIAlign: mask-weighted RoIAlign.
//   features: [N=2, C=256, H=200, W=200] f32 (NCHW)
//   rois:     [R=512, 5] f32  (b, x1, y1, x2, y2) inclusive image coords
//   masks:    [R, MH=128, MW=128] f32
//   out:      [R, C, 7, 7] f32
// out[r,c,ph,pw] = mean over 2x2 sub-samples of
//   bilinear(features[b,c], y, x) * bilinear(mask[r], y/SCALE - y1, x/SCALE - x1)

constexpr int   OUT_H = 7, OUT_W = 7;
constexpr float SCALE = 0.25f;
constexpr int   S     = 2;

// Bilinear sample with RoIAlign semantics (zero outside (-1,H)x(-1,W)).
__device__ __forceinline__ float bilinear(const float* __restrict__ img,
                                          int Hh, int Ww, float y, float x) {
    bool valid = (y > -1.0f) && (y < (float)Hh) && (x > -1.0f) && (x < (float)Ww);
    if (!valid) return 0.0f;
    y = fminf(fmaxf(y, 0.0f), (float)(Hh - 1));
    x = fminf(fmaxf(x, 0.0f), (float)(Ww - 1));
    int y0 = (int)floorf(y);
    int x0 = (int)floorf(x);
    int y1 = min(y0 + 1, Hh - 1);
    int x1 = min(x0 + 1, Ww - 1);
    float ly = y - (float)y0, lx = x - (float)x0;
    float hy = 1.0f - ly,     hx = 1.0f - lx;
    return hy * hx * img[y0 * Ww + x0] + hy * lx * img[y0 * Ww + x1]
         + ly * hx * img[y1 * Ww + x0] + ly * lx * img[y1 * Ww + x1];
}

// One block per (roi, ph, pw); one thread per channel.
// Weight math (mask bilinear + corner indices) is channel-independent and
// recomputed per thread — ~120 VALU ops, negligible vs the scattered loads.
__global__ __launch_bounds__(256)
void mask_roialign_kernel(const float* __restrict__ features,
                          const float* __restrict__ rois,
                          const float* __restrict__ masks,
                          float*       __restrict__ out,
                          int C, int H, int W, int MH, int MW) {
    int blk = blockIdx.x;
    int pw  = blk % OUT_W;
    int ph  = (blk / OUT_W) % OUT_H;
    int r   = blk / (OUT_W * OUT_H);
    int c   = threadIdx.x;

    const float* roi = rois + (size_t)r * 5;
    int   b  = (int)roi[0];
    float x1 = roi[1], y1 = roi[2], x2 = roi[3], y2 = roi[4];

    float roi_start_w = x1 * SCALE;
    float roi_start_h = y1 * SCALE;
    float roi_w = fmaxf((x2 - x1 + 1.0f) * SCALE, 1.0f);
    float roi_h = fmaxf((y2 - y1 + 1.0f) * SCALE, 1.0f);
    float bin_w = roi_w / (float)OUT_W;
    float bin_h = roi_h / (float)OUT_H;

    const float* fch = features + ((size_t)b * C + c) * (size_t)(H * W);
    const float* msk = masks + (size_t)r * MH * MW;

    float acc = 0.0f;
#pragma unroll
    for (int iy = 0; iy < S; ++iy) {
        float yy = roi_start_h + ((float)ph + ((float)iy + 0.5f) / (float)S) * bin_h;
#pragma unroll
        for (int ix = 0; ix < S; ++ix) {
            float xx = roi_start_w + ((float)pw + ((float)ix + 0.5f) / (float)S) * bin_w;

            // validity of the FEATURE sample (uniform across block -> no divergence)
            bool valid = (yy > -1.0f) && (yy < (float)H) && (xx > -1.0f) && (xx < (float)W);

            // mask weight at the same point, roi-relative image coords
            float my = fminf(fmaxf(yy / SCALE - y1, 0.0f), y2 - y1);
            float mx = fminf(fmaxf(xx / SCALE - x1, 0.0f), x2 - x1);
            float wgt = bilinear(msk, MH, MW, my, mx);

            if (valid) {
                float yc = fminf(fmaxf(yy, 0.0f), (float)(H - 1));
                float xc = fminf(fmaxf(xx, 0.0f), (float)(W - 1));
                int y0  = (int)floorf(yc);
                int x0  = (int)floorf(xc);
                int y1i = min(y0 + 1, H - 1);
                int x1i = min(x0 + 1, W - 1);
                float ly = yc - (float)y0, lx = xc - (float)x0;
                float hy = 1.0f - ly,     hx = 1.0f - lx;
                float v = hy * hx * fch[y0  * W + x0 ] + hy * lx * fch[y0  * W + x1i]
                        + ly * hx * fch[y1i * W + x0 ] + ly * lx * fch[y1i * W + x1i];
                acc += wgt * v;
            }
        }
    }

    out[((size_t)r * C + c) * (OUT_H * OUT_W) + ph * OUT_W + pw] =
        acc * (1.0f / (float)(S * S));
}

extern "C" void kernel_launch(void* const* d_in, const int* in_sizes, int n_in,
                              void* d_out, int out_size, void* d_ws, size_t ws_size,
                              hipStream_t stream) {
    const float* features = (const float*)d_in[0];
    const float* rois     = (const float*)d_in[1];
    const float* masks    = (const float*)d_in[2];
    float*       out      = (float*)d_out;

    const int R  = in_sizes[1] / 5;                       // 512
    const int C  = out_size / (R * OUT_H * OUT_W);        // 256
    const int H  = 200, W = 200;                          // fixed by reference
    const int MH = 128, MW = 128;                         // fixed by reference

    dim3 grid(R * OUT_H * OUT_W);   // 25088 blocks
    dim3 block(C);                  // 256 threads = 1 channel each
    mask_roialign_kernel<<<grid, block, 0, stream>>>(features, rois, masks, out,
                                                     C, H, W, MH, MW);
}

// Round 3
// 190.617 us; speedup vs baseline: 4.0645x; 4.0645x over previous
//
#include <hip/hip_runtime.h>

// ShapeAwareRoIAlign: mask-weighted RoIAlign.
//   features: [N=2, C=256, H=200, W=200] f32 (NCHW)
//   rois:     [R=512, 5] f32  (b, x1, y1, x2, y2) inclusive image coords
//   masks:    [R, MH=128, MW=128] f32
//   out:      [R, C, 7, 7] f32
//
// Round 3 plan: NCHW gather had 12x read amplification (FETCH 1.96 GB) and
// 11x write amplification (WRITE 283 MB). Fix: transpose features to NHWC in
// d_ws (kernel 1), then one-block-per-roi kernel with LDS-staged sample
// weights, coalesced channel gathers, and LDS-staged coalesced output writes.

constexpr int   OUT_H = 7, OUT_W = 7;
constexpr int   NBIN  = OUT_H * OUT_W;   // 49
constexpr float SCALE = 0.25f;
constexpr int   S     = 2;
constexpr int   NSAMP = NBIN * S * S;    // 196 sample points per roi

// ---------------------------------------------------------------------------
// Kernel 1: NCHW -> NHWC transpose.  Treat as per-batch 2D transpose of
// [C, P=H*W]: in[b][c][p] -> out[b][p][c]. 32x32 LDS tile, both sides coalesced.
// ---------------------------------------------------------------------------
__global__ __launch_bounds__(256)
void nchw_to_nhwc_kernel(const float* __restrict__ in, float* __restrict__ out,
                         int C, int P) {
    __shared__ float tile[32][33];
    int tx = threadIdx.x;          // 0..31
    int ty = threadIdx.y;          // 0..7
    int gx = blockIdx.x * 32;      // p-dim base
    int gy = blockIdx.y * 32;      // c-dim base
    int b  = blockIdx.z;

    const float* inb  = in  + (size_t)b * C * P;
    float*       outb = out + (size_t)b * C * P;

#pragma unroll
    for (int j = 0; j < 4; ++j) {
        int cc = gy + ty + 8 * j;
        int p  = gx + tx;
        if (cc < C && p < P)
            tile[ty + 8 * j][tx] = inb[(size_t)cc * P + p];
    }
    __syncthreads();
#pragma unroll
    for (int j = 0; j < 4; ++j) {
        int p  = gx + ty + 8 * j;
        int cc = gy + tx;
        if (cc < C && p < P)
            outb[(size_t)p * C + cc] = tile[tx][ty + 8 * j];
    }
}

// ---------------------------------------------------------------------------
// Kernel 2: one block per roi, 256 threads (= channels).
// Stage: 196 threads precompute per-sample corner offsets (NHWC element
// offsets) and folded weights (bilinear_corner * mask_wgt * valid * 0.25).
// Compute: thread c accumulates its channel over 4 samples x 4 corners per
// bin — loads nhwc[off + c] are lane-contiguous (coalesced).
// Epilogue: [C][49] tile staged in LDS, written out linearly (coalesced).
// ---------------------------------------------------------------------------
__global__ __launch_bounds__(256)
void mask_roialign_nhwc_kernel(const float* __restrict__ nhwc,
                               const float* __restrict__ rois,
                               const float* __restrict__ masks,
                               float*       __restrict__ out,
                               int C, int H, int W, int MH, int MW) {
    __shared__ int   s_off[NSAMP][4];
    __shared__ float s_w[NSAMP][4];
    __shared__ float s_out[256 * NBIN];   // [c][bin], 50 kB

    const int r   = blockIdx.x;
    const int tid = threadIdx.x;

    const float* roi = rois + (size_t)r * 5;
    const int   b  = (int)roi[0];
    const float x1 = roi[1], y1 = roi[2], x2 = roi[3], y2 = roi[4];

    // ---- stage: per-sample geometry (threads 0..195) ----
    if (tid < NSAMP) {
        const int bin = tid >> 2;          // 0..48
        const int sub = tid & 3;           // 0..3
        const int ph  = bin / OUT_W, pw = bin % OUT_W;
        const int iy  = sub >> 1,   ix = sub & 1;

        const float roi_start_w = x1 * SCALE;
        const float roi_start_h = y1 * SCALE;
        const float roi_w = fmaxf((x2 - x1 + 1.0f) * SCALE, 1.0f);
        const float roi_h = fmaxf((y2 - y1 + 1.0f) * SCALE, 1.0f);
        const float bin_w = roi_w / (float)OUT_W;
        const float bin_h = roi_h / (float)OUT_H;

        const float yy = roi_start_h + ((float)ph + ((float)iy + 0.5f) * (1.0f / S)) * bin_h;
        const float xx = roi_start_w + ((float)pw + ((float)ix + 0.5f) * (1.0f / S)) * bin_w;

        const bool valid = (yy > -1.0f) && (yy < (float)H) && (xx > -1.0f) && (xx < (float)W);

        // mask weight (roi-relative image coords; always in-bounds after clip)
        const float* msk = masks + (size_t)r * MH * MW;
        float my = fminf(fmaxf(yy * (1.0f / SCALE) - y1, 0.0f), y2 - y1);
        float mx = fminf(fmaxf(xx * (1.0f / SCALE) - x1, 0.0f), x2 - x1);
        {
            // bilinear on the mask
            my = fminf(fmaxf(my, 0.0f), (float)(MH - 1));
            mx = fminf(fmaxf(mx, 0.0f), (float)(MW - 1));
        }
        const int my0 = (int)floorf(my), mx0 = (int)floorf(mx);
        const int my1 = min(my0 + 1, MH - 1), mx1 = min(mx0 + 1, MW - 1);
        const float mly = my - (float)my0, mlx = mx - (float)mx0;
        const float mhy = 1.0f - mly,      mhx = 1.0f - mlx;
        const float wgt = mhy * mhx * msk[my0 * MW + mx0] + mhy * mlx * msk[my0 * MW + mx1]
                        + mly * mhx * msk[my1 * MW + mx0] + mly * mlx * msk[my1 * MW + mx1];

        // feature corner offsets + folded weights
        const float yc = fminf(fmaxf(yy, 0.0f), (float)(H - 1));
        const float xc = fminf(fmaxf(xx, 0.0f), (float)(W - 1));
        const int y0  = (int)floorf(yc), x0 = (int)floorf(xc);
        const int y1i = min(y0 + 1, H - 1), x1i = min(x0 + 1, W - 1);
        const float ly = yc - (float)y0, lx = xc - (float)x0;
        const float hy = 1.0f - ly,      hx = 1.0f - lx;

        const float scale_all = (valid ? wgt : 0.0f) * (1.0f / (float)(S * S));
        s_w[tid][0] = hy * hx * scale_all;
        s_w[tid][1] = hy * lx * scale_all;
        s_w[tid][2] = ly * hx * scale_all;
        s_w[tid][3] = ly * lx * scale_all;
        s_off[tid][0] = (y0  * W + x0 ) * C;
        s_off[tid][1] = (y0  * W + x1i) * C;
        s_off[tid][2] = (y1i * W + x0 ) * C;
        s_off[tid][3] = (y1i * W + x1i) * C;
    }
    __syncthreads();

    // ---- compute: lane = channel ----
    const int c = tid;
    const float* f = nhwc + (size_t)b * H * W * C + c;

    for (int bin = 0; bin < NBIN; ++bin) {
        float acc = 0.0f;
#pragma unroll
        for (int sub = 0; sub < 4; ++sub) {
            const int s = bin * 4 + sub;
            // broadcast LDS reads (uniform address across wave -> free)
            const int   o0 = s_off[s][0], o1 = s_off[s][1], o2 = s_off[s][2], o3 = s_off[s][3];
            const float w0 = s_w[s][0],   w1 = s_w[s][1],   w2 = s_w[s][2],   w3 = s_w[s][3];
            acc += w0 * f[o0] + w1 * f[o1] + w2 * f[o2] + w3 * f[o3];
        }
        s_out[c * NBIN + bin] = acc;
    }
    __syncthreads();

    // ---- epilogue: coalesced linear write of the [C*49] tile ----
    float* outr = out + (size_t)r * C * NBIN;
    const float4* s4 = (const float4*)s_out;
    float4*       o4 = (float4*)outr;
    const int nvec = (256 * NBIN) / 4;     // 3136
    for (int i = tid; i < nvec; i += 256)
        o4[i] = s4[i];
}

// ---------------------------------------------------------------------------
// Fallback (round-2 baseline) if d_ws can't hold the NHWC copy.
// ---------------------------------------------------------------------------
__global__ __launch_bounds__(256)
void mask_roialign_kernel(const float* __restrict__ features,
                          const float* __restrict__ rois,
                          const float* __restrict__ masks,
                          float*       __restrict__ out,
                          int C, int H, int W, int MH, int MW) {
    int blk = blockIdx.x;
    int pw  = blk % OUT_W;
    int ph  = (blk / OUT_W) % OUT_H;
    int r   = blk / (OUT_W * OUT_H);
    int c   = threadIdx.x;

    const float* roi = rois + (size_t)r * 5;
    int   b  = (int)roi[0];
    float x1 = roi[1], y1 = roi[2], x2 = roi[3], y2 = roi[4];

    float roi_start_w = x1 * SCALE;
    float roi_start_h = y1 * SCALE;
    float roi_w = fmaxf((x2 - x1 + 1.0f) * SCALE, 1.0f);
    float roi_h = fmaxf((y2 - y1 + 1.0f) * SCALE, 1.0f);
    float bin_w = roi_w / (float)OUT_W;
    float bin_h = roi_h / (float)OUT_H;

    const float* fch = features + ((size_t)b * C + c) * (size_t)(H * W);
    const float* msk = masks + (size_t)r * MH * MW;

    float acc = 0.0f;
#pragma unroll
    for (int iy = 0; iy < S; ++iy) {
        float yy = roi_start_h + ((float)ph + ((float)iy + 0.5f) / (float)S) * bin_h;
#pragma unroll
        for (int ix = 0; ix < S; ++ix) {
            float xx = roi_start_w + ((float)pw + ((float)ix + 0.5f) / (float)S) * bin_w;
            bool valid = (yy > -1.0f) && (yy < (float)H) && (xx > -1.0f) && (xx < (float)W);
            float my = fminf(fmaxf(yy / SCALE - y1, 0.0f), fminf(y2 - y1, (float)(MH - 1)));
            float mx = fminf(fmaxf(xx / SCALE - x1, 0.0f), fminf(x2 - x1, (float)(MW - 1)));
            int my0 = (int)floorf(my), mx0 = (int)floorf(mx);
            int my1 = min(my0 + 1, MH - 1), mx1 = min(mx0 + 1, MW - 1);
            float mly = my - my0, mlx = mx - mx0, mhy = 1.0f - mly, mhx = 1.0f - mlx;
            float wgt = mhy * mhx * msk[my0 * MW + mx0] + mhy * mlx * msk[my0 * MW + mx1]
                      + mly * mhx * msk[my1 * MW + mx0] + mly * mlx * msk[my1 * MW + mx1];
            if (valid) {
                float yc = fminf(fmaxf(yy, 0.0f), (float)(H - 1));
                float xc = fminf(fmaxf(xx, 0.0f), (float)(W - 1));
                int y0 = (int)floorf(yc), x0 = (int)floorf(xc);
                int y1i = min(y0 + 1, H - 1), x1i = min(x0 + 1, W - 1);
                float ly = yc - y0, lx = xc - x0, hy = 1.0f - ly, hx = 1.0f - lx;
                float v = hy * hx * fch[y0  * W + x0 ] + hy * lx * fch[y0  * W + x1i]
                        + ly * hx * fch[y1i * W + x0 ] + ly * lx * fch[y1i * W + x1i];
                acc += wgt * v;
            }
        }
    }
    out[((size_t)r * C + c) * (size_t)NBIN + ph * OUT_W + pw] = acc * (1.0f / (S * S));
}

extern "C" void kernel_launch(void* const* d_in, const int* in_sizes, int n_in,
                              void* d_out, int out_size, void* d_ws, size_t ws_size,
                              hipStream_t stream) {
    const float* features = (const float*)d_in[0];
    const float* rois     = (const float*)d_in[1];
    const float* masks    = (const float*)d_in[2];
    float*       out      = (float*)d_out;

    const int R  = in_sizes[1] / 5;                       // 512
    const int C  = out_size / (R * NBIN);                 // 256
    const int H  = 200, W = 200;                          // fixed by reference
    const int MH = 128, MW = 128;                         // fixed by reference
    const int N  = in_sizes[0] / (C * H * W);             // 2
    const int P  = H * W;

    const size_t need = (size_t)N * C * P * sizeof(float);  // 164 MB
    if (ws_size >= need) {
        float* nhwc = (float*)d_ws;
        dim3 tb(32, 8);
        dim3 tg((P + 31) / 32, (C + 31) / 32, N);
        nchw_to_nhwc_kernel<<<tg, tb, 0, stream>>>(features, nhwc, C, P);

        mask_roialign_nhwc_kernel<<<dim3(R), dim3(256), 0, stream>>>(
            nhwc, rois, masks, out, C, H, W, MH, MW);
    } else {
        mask_roialign_kernel<<<dim3(R * NBIN), dim3(256), 0, stream>>>(
            features, rois, masks, out, C, H, W, MH, MW);
    }
}

// Round 4
// 182.638 us; speedup vs baseline: 4.2421x; 1.0437x over previous
//
#include <hip/hip_runtime.h>

// ShapeAwareRoIAlign: mask-weighted RoIAlign.
//   features: [N=2, C=256, H=200, W=200] f32 (NCHW, 82 MB)
//   rois:     [R=512, 5] f32  (b, x1, y1, x2, y2) inclusive image coords
//   masks:    [R, MH=128, MW=128] f32
//   out:      [R, C, 7, 7] f32
//
// Round 4: (a) float4-vectorized 64x64 transpose (was 2.5 TB/s @ 4B/lane);
// (b) main kernel split into 8 channel-group blocks per roi (grid R x 8) for
// 4x occupancy (2 -> 8 blocks/CU) while keeping output writes contiguous.

constexpr int   OUT_H = 7, OUT_W = 7;
constexpr int   NBIN  = OUT_H * OUT_W;   // 49
constexpr float SCALE = 0.25f;
constexpr int   S     = 2;
constexpr int   NSAMP = NBIN * S * S;    // 196 sample points per roi
constexpr int   CG    = 32;              // channels per block in main kernel

// ---------------------------------------------------------------------------
// Kernel 1: NCHW -> NHWC transpose, float4 on both global sides.
// Per-batch 2D transpose of [C, P=H*W]. 64x64 tile, 256 threads (16x16).
// LDS rowstride 65 (scalar stores/loads): store lanes stride 4 banks (2-way,
// free); column reads stride 260 % 32 = 4 banks (2-way, free).
// Requires C%64==0 and P%64==0 (256, 40000: both hold).
// ---------------------------------------------------------------------------
__global__ __launch_bounds__(256)
void nchw_to_nhwc_v4_kernel(const float* __restrict__ in, float* __restrict__ out,
                            int C, int P) {
    __shared__ float tile[64][65];
    const int tx = threadIdx.x;        // 0..15
    const int ty = threadIdx.y;        // 0..15
    const int gx = blockIdx.x * 64;    // p base
    const int gy = blockIdx.y * 64;    // c base
    const int b  = blockIdx.z;

    const float* inb  = in  + (size_t)b * C * P;
    float*       outb = out + (size_t)b * C * P;

#pragma unroll
    for (int j = 0; j < 4; ++j) {
        const int c_local = ty + 16 * j;
        const float4 v = *(const float4*)&inb[(size_t)(gy + c_local) * P + gx + 4 * tx];
        tile[c_local][4 * tx + 0] = v.x;
        tile[c_local][4 * tx + 1] = v.y;
        tile[c_local][4 * tx + 2] = v.z;
        tile[c_local][4 * tx + 3] = v.w;
    }
    __syncthreads();
#pragma unroll
    for (int j = 0; j < 4; ++j) {
        const int p_local = ty + 16 * j;
        float4 v;
        v.x = tile[4 * tx + 0][p_local];
        v.y = tile[4 * tx + 1][p_local];
        v.z = tile[4 * tx + 2][p_local];
        v.w = tile[4 * tx + 3][p_local];
        *(float4*)&outb[(size_t)(gx + p_local) * C + gy + 4 * tx] = v;
    }
}

// ---------------------------------------------------------------------------
// Kernel 2: grid (R, C/32). Block = 256 threads handles 32 channels x 49 bins.
// Stage: threads 0..195 precompute per-sample corner offsets + folded weights
// (bilinear * mask * valid * 0.25) into LDS (redundant across the 8
// channel-group blocks of a roi — cheap, mask lines are cache-hot).
// Compute: tid = bg*32 + cl; bg in [0,8) covers bins {bg, bg+8, ...};
// cl = channel within group. Gathers are 128 B contiguous per half-wave.
// Epilogue: [32][49] tile staged in LDS -> one contiguous 6.3 kB write.
// ---------------------------------------------------------------------------
__global__ __launch_bounds__(256)
void mask_roialign_nhwc_kernel(const float* __restrict__ nhwc,
                               const float* __restrict__ rois,
                               const float* __restrict__ masks,
                               float*       __restrict__ out,
                               int C, int H, int W, int MH, int MW) {
    __shared__ int   s_off[NSAMP][4];
    __shared__ float s_w[NSAMP][4];
    __shared__ float s_out[CG * NBIN];   // [cl][bin], 6.3 kB

    const int r   = blockIdx.x;
    const int cg  = blockIdx.y;          // channel group
    const int tid = threadIdx.x;

    const float* roi = rois + (size_t)r * 5;
    const int   b  = (int)roi[0];
    const float x1 = roi[1], y1 = roi[2], x2 = roi[3], y2 = roi[4];

    // ---- stage: per-sample geometry (threads 0..195) ----
    if (tid < NSAMP) {
        const int bin = tid >> 2;          // 0..48
        const int sub = tid & 3;           // 0..3
        const int ph  = bin / OUT_W, pw = bin % OUT_W;
        const int iy  = sub >> 1,   ix = sub & 1;

        const float roi_start_w = x1 * SCALE;
        const float roi_start_h = y1 * SCALE;
        const float roi_w = fmaxf((x2 - x1 + 1.0f) * SCALE, 1.0f);
        const float roi_h = fmaxf((y2 - y1 + 1.0f) * SCALE, 1.0f);
        const float bin_w = roi_w / (float)OUT_W;
        const float bin_h = roi_h / (float)OUT_H;

        const float yy = roi_start_h + ((float)ph + ((float)iy + 0.5f) * (1.0f / S)) * bin_h;
        const float xx = roi_start_w + ((float)pw + ((float)ix + 0.5f) * (1.0f / S)) * bin_w;

        const bool valid = (yy > -1.0f) && (yy < (float)H) && (xx > -1.0f) && (xx < (float)W);

        // mask weight (roi-relative image coords)
        const float* msk = masks + (size_t)r * MH * MW;
        float my = fminf(fmaxf(yy * (1.0f / SCALE) - y1, 0.0f), y2 - y1);
        float mx = fminf(fmaxf(xx * (1.0f / SCALE) - x1, 0.0f), x2 - x1);
        my = fminf(fmaxf(my, 0.0f), (float)(MH - 1));
        mx = fminf(fmaxf(mx, 0.0f), (float)(MW - 1));
        const int my0 = (int)floorf(my), mx0 = (int)floorf(mx);
        const int my1 = min(my0 + 1, MH - 1), mx1 = min(mx0 + 1, MW - 1);
        const float mly = my - (float)my0, mlx = mx - (float)mx0;
        const float mhy = 1.0f - mly,      mhx = 1.0f - mlx;
        const float wgt = mhy * mhx * msk[my0 * MW + mx0] + mhy * mlx * msk[my0 * MW + mx1]
                        + mly * mhx * msk[my1 * MW + mx0] + mly * mlx * msk[my1 * MW + mx1];

        // feature corner offsets + folded weights
        const float yc = fminf(fmaxf(yy, 0.0f), (float)(H - 1));
        const float xc = fminf(fmaxf(xx, 0.0f), (float)(W - 1));
        const int y0  = (int)floorf(yc), x0 = (int)floorf(xc);
        const int y1i = min(y0 + 1, H - 1), x1i = min(x0 + 1, W - 1);
        const float ly = yc - (float)y0, lx = xc - (float)x0;
        const float hy = 1.0f - ly,      hx = 1.0f - lx;

        const float scale_all = (valid ? wgt : 0.0f) * (1.0f / (float)(S * S));
        s_w[tid][0] = hy * hx * scale_all;
        s_w[tid][1] = hy * lx * scale_all;
        s_w[tid][2] = ly * hx * scale_all;
        s_w[tid][3] = ly * lx * scale_all;
        s_off[tid][0] = (y0  * W + x0 ) * C;
        s_off[tid][1] = (y0  * W + x1i) * C;
        s_off[tid][2] = (y1i * W + x0 ) * C;
        s_off[tid][3] = (y1i * W + x1i) * C;
    }
    __syncthreads();

    // ---- compute: tid = bg*32 + cl ----
    const int cl = tid & (CG - 1);       // channel within group
    const int bg = tid >> 5;             // bin-group 0..7
    const int c  = cg * CG + cl;
    const float* f = nhwc + (size_t)b * H * W * C + c;

    for (int bin = bg; bin < NBIN; bin += 8) {
        float acc = 0.0f;
#pragma unroll
        for (int sub = 0; sub < 4; ++sub) {
            const int s = bin * 4 + sub;
            const int   o0 = s_off[s][0], o1 = s_off[s][1], o2 = s_off[s][2], o3 = s_off[s][3];
            const float w0 = s_w[s][0],   w1 = s_w[s][1],   w2 = s_w[s][2],   w3 = s_w[s][3];
            acc += w0 * f[o0] + w1 * f[o1] + w2 * f[o2] + w3 * f[o3];
        }
        s_out[cl * NBIN + bin] = acc;
    }
    __syncthreads();

    // ---- epilogue: contiguous 32*49-float tile write ----
    float* outr = out + ((size_t)r * C + (size_t)cg * CG) * NBIN;
    const int ntot = CG * NBIN;          // 1568
    const float4* s4 = (const float4*)s_out;
    float4*       o4 = (float4*)outr;
    for (int i = tid; i < ntot / 4; i += 256)    // 392 float4s
        o4[i] = s4[i];
}

// ---------------------------------------------------------------------------
// Fallback (round-2 baseline) if d_ws can't hold the NHWC copy.
// ---------------------------------------------------------------------------
__global__ __launch_bounds__(256)
void mask_roialign_kernel(const float* __restrict__ features,
                          const float* __restrict__ rois,
                          const float* __restrict__ masks,
                          float*       __restrict__ out,
                          int C, int H, int W, int MH, int MW) {
    int blk = blockIdx.x;
    int pw  = blk % OUT_W;
    int ph  = (blk / OUT_W) % OUT_H;
    int r   = blk / (OUT_W * OUT_H);
    int c   = threadIdx.x;

    const float* roi = rois + (size_t)r * 5;
    int   b  = (int)roi[0];
    float x1 = roi[1], y1 = roi[2], x2 = roi[3], y2 = roi[4];

    float roi_start_w = x1 * SCALE;
    float roi_start_h = y1 * SCALE;
    float roi_w = fmaxf((x2 - x1 + 1.0f) * SCALE, 1.0f);
    float roi_h = fmaxf((y2 - y1 + 1.0f) * SCALE, 1.0f);
    float bin_w = roi_w / (float)OUT_W;
    float bin_h = roi_h / (float)OUT_H;

    const float* fch = features + ((size_t)b * C + c) * (size_t)(H * W);
    const float* msk = masks + (size_t)r * MH * MW;

    float acc = 0.0f;
#pragma unroll
    for (int iy = 0; iy < S; ++iy) {
        float yy = roi_start_h + ((float)ph + ((float)iy + 0.5f) / (float)S) * bin_h;
#pragma unroll
        for (int ix = 0; ix < S; ++ix) {
            float xx = roi_start_w + ((float)pw + ((float)ix + 0.5f) / (float)S) * bin_w;
            bool valid = (yy > -1.0f) && (yy < (float)H) && (xx > -1.0f) && (xx < (float)W);
            float my = fminf(fmaxf(yy / SCALE - y1, 0.0f), fminf(y2 - y1, (float)(MH - 1)));
            float mx = fminf(fmaxf(xx / SCALE - x1, 0.0f), fminf(x2 - x1, (float)(MW - 1)));
            int my0 = (int)floorf(my), mx0 = (int)floorf(mx);
            int my1 = min(my0 + 1, MH - 1), mx1 = min(mx0 + 1, MW - 1);
            float mly = my - my0, mlx = mx - mx0, mhy = 1.0f - mly, mhx = 1.0f - mlx;
            float wgt = mhy * mhx * msk[my0 * MW + mx0] + mhy * mlx * msk[my0 * MW + mx1]
                      + mly * mhx * msk[my1 * MW + mx0] + mly * mlx * msk[my1 * MW + mx1];
            if (valid) {
                float yc = fminf(fmaxf(yy, 0.0f), (float)(H - 1));
                float xc = fminf(fmaxf(xx, 0.0f), (float)(W - 1));
                int y0 = (int)floorf(yc), x0 = (int)floorf(xc);
                int y1i = min(y0 + 1, H - 1), x1i = min(x0 + 1, W - 1);
                float ly = yc - y0, lx = xc - x0, hy = 1.0f - ly, hx = 1.0f - lx;
                float v = hy * hx * fch[y0  * W + x0 ] + hy * lx * fch[y0  * W + x1i]
                        + ly * hx * fch[y1i * W + x0 ] + ly * lx * fch[y1i * W + x1i];
                acc += wgt * v;
            }
        }
    }
    out[((size_t)r * C + c) * (size_t)NBIN + ph * OUT_W + pw] = acc * (1.0f / (S * S));
}

extern "C" void kernel_launch(void* const* d_in, const int* in_sizes, int n_in,
                              void* d_out, int out_size, void* d_ws, size_t ws_size,
                              hipStream_t stream) {
    const float* features = (const float*)d_in[0];
    const float* rois     = (const float*)d_in[1];
    const float* masks    = (const float*)d_in[2];
    float*       out      = (float*)d_out;

    const int R  = in_sizes[1] / 5;                       // 512
    const int C  = out_size / (R * NBIN);                 // 256
    const int H  = 200, W = 200;                          // fixed by reference
    const int MH = 128, MW = 128;                         // fixed by reference
    const int N  = in_sizes[0] / (C * H * W);             // 2
    const int P  = H * W;                                 // 40000

    const size_t need = (size_t)N * C * P * sizeof(float);  // 82 MB
    const bool tiles_ok = (C % 64 == 0) && (P % 64 == 0) && (C % CG == 0);
    if (ws_size >= need && tiles_ok) {
        float* nhwc = (float*)d_ws;
        dim3 tb(16, 16);
        dim3 tg(P / 64, C / 64, N);                       // 625 x 4 x 2
        nchw_to_nhwc_v4_kernel<<<tg, tb, 0, stream>>>(features, nhwc, C, P);

        mask_roialign_nhwc_kernel<<<dim3(R, C / CG), dim3(256), 0, stream>>>(
            nhwc, rois, masks, out, C, H, W, MH, MW);
    } else {
        mask_roialign_kernel<<<dim3(R * NBIN), dim3(256), 0, stream>>>(
            features, rois, masks, out, C, H, W, MH, MW);
    }
}